// Round 4
// baseline (389.482 us; speedup 1.0000x reference)
//
#include <hip/hip_runtime.h>

typedef float f32x4 __attribute__((ext_vector_type(4)));

namespace {
constexpr int   B_    = 2;
constexpr int   N_    = 250000;
constexpr int   C_    = 64;
constexpr int   NX_   = 1024;
constexpr int   NY_   = 1024;
constexpr int   CELLS = NX_ * NY_;          // 1<<20
constexpr float VS0   = 0.1f, VS1 = 0.1f;
constexpr float PC0   = -51.2f, PC1 = -51.2f;
constexpr float EPS_  = 1e-5f;
constexpr int   RBLK  = 256;

// ---- d_ws layout (4B units) ----
constexpr int WS_W1T  = 0;                   // [64][10]
constexpr int WS_B1   = 640;                 // [64]
constexpr int WS_W2T  = 704;                 // [64][64] (c-major rows)
constexpr int WS_B2   = 4800;                // [64]
constexpr int WS_ZM   = 4864;                // [B]
constexpr int WS_PZ   = 4872;                // [B][RBLK]
constexpr int WS_PM   = WS_PZ + B_ * RBLK;   // [B][RBLK]
constexpr int WS_CNT  = WS_PM + B_ * RBLK;   // occupied-cell counter
constexpr int WS_HIST = 8192;                // [B*CELLS] counts -> exclusive offsets
constexpr int TOT     = B_ * CELLS;          // 2,097,152
constexpr int WS_CUR  = WS_HIST + TOT;       // [B*CELLS] write cursors
constexpr int WS_PART = WS_CUR + TOT;        // [1024] scan partials
constexpr int WS_CELL = WS_PART + 2048;      // [B*N] per-point cell idx (-1 invalid)
constexpr int WS_IDS  = WS_CELL + B_ * N_;   // [<=B*N] sorted point ids
constexpr int WS_LIST = WS_IDS + B_ * N_;    // [<=B*N] occupied cell list
constexpr int WS_END  = WS_LIST + B_ * N_;
constexpr size_t NEED_BYTES = (size_t)WS_END * 4;
}

// Zero the 536 MB output + 8.4 MB histogram with streaming NT stores
// (rocclr's fillBuffer ran at 26 GB/s for the small fill; do it ourselves).
__global__ __launch_bounds__(256) void zero_bufs(f32x4* __restrict__ out4,
                                                 f32x4* __restrict__ hist4) {
    const int tid    = blockIdx.x * 256 + threadIdx.x;
    const int stride = gridDim.x * 256;
    constexpr int N4 = (B_ * C_ * CELLS) / 4;   // 33,554,432
    constexpr int H4 = TOT / 4;                 // 524,288
    const f32x4 z = {0.f, 0.f, 0.f, 0.f};
    for (int i = tid; i < N4; i += stride) __builtin_nontemporal_store(z, out4 + i);
    for (int i = tid; i < H4; i += stride) __builtin_nontemporal_store(z, hist4 + i);
}

// ---------------- common prep ----------------
__global__ void prep_weights(const float* __restrict__ W1, const float* __restrict__ g1,
                             const float* __restrict__ b1, const float* __restrict__ m1,
                             const float* __restrict__ v1, const float* __restrict__ W2,
                             const float* __restrict__ g2, const float* __restrict__ b2,
                             const float* __restrict__ m2, const float* __restrict__ v2,
                             float* __restrict__ ws) {
    int c = threadIdx.x;
    if (c == 0) ((int*)ws)[WS_CNT] = 0;
    if (c >= C_) return;
    float s1 = g1[c] / sqrtf(v1[c] + EPS_);
    for (int f = 0; f < 10; ++f) ws[WS_W1T + c * 10 + f] = W1[f * C_ + c] * s1;
    ws[WS_B1 + c] = b1[c] - m1[c] * s1;
    float s2 = g2[c] / sqrtf(v2[c] + EPS_);
    for (int k = 0; k < C_; ++k) ws[WS_W2T + c * C_ + k] = W2[k * C_ + c] * s2;
    ws[WS_B2 + c] = b2[c] - m2[c] * s2;
}

__device__ __forceinline__ int cell_of(float x, float y) {
    int px = (int)floorf((x - PC0) / VS0);
    int py = (int)floorf((y - PC1) / VS1);
    px = px < 0 ? 0 : (px > NX_ - 1 ? NX_ - 1 : px);
    py = py < 0 ? 0 : (py > NY_ - 1 ? NY_ - 1 : py);
    return py * NX_ + px;
}

// ---------------- sorted path ----------------
// Fused: z-mean partials + per-point cell id + histogram.
__global__ void zmean_hist_cell(const float* __restrict__ pts, const int* __restrict__ mask,
                                float* __restrict__ wsf, int* __restrict__ wsi) {
    const int b = blockIdx.y, r = blockIdx.x, t = threadIdx.x;
    constexpr int chunk = (N_ + RBLK - 1) / RBLK;
    const int start = r * chunk;
    const int end   = start + chunk < N_ ? start + chunk : N_;
    float sz = 0.f, sm = 0.f;
    for (int n = start + t; n < end; n += 256) {
        const int mk = mask[b * N_ + n];
        const size_t pb = ((size_t)b * N_ + n) * 5;
        const float x = pts[pb], y = pts[pb + 1], z = pts[pb + 2];
        const int idx = b * CELLS + cell_of(x, y);
        wsi[WS_CELL + b * N_ + n] = mk ? idx : -1;
        if (mk) {
            atomicAdd(&wsi[WS_HIST + idx], 1);
            sz += z; sm += 1.f;
        }
    }
    __shared__ float lz[256], lm[256];
    lz[t] = sz; lm[t] = sm;
    __syncthreads();
    for (int s = 128; s > 0; s >>= 1) {
        if (t < s) { lz[t] += lz[t + s]; lm[t] += lm[t + s]; }
        __syncthreads();
    }
    if (t == 0) { wsf[WS_PZ + b * RBLK + r] = lz[0]; wsf[WS_PM + b * RBLK + r] = lm[0]; }
}

__global__ void zmean_stage2(float* __restrict__ ws) {
    const int b = blockIdx.x, t = threadIdx.x;
    __shared__ float lz[256], lm[256];
    lz[t] = ws[WS_PZ + b * RBLK + t];
    lm[t] = ws[WS_PM + b * RBLK + t];
    __syncthreads();
    for (int s = 128; s > 0; s >>= 1) {
        if (t < s) { lz[t] += lz[t + s]; lm[t] += lm[t + s]; }
        __syncthreads();
    }
    if (t == 0) ws[WS_ZM + b] = lz[0] / fmaxf(lm[0], 1.f);
}

// Scan stage 1: per-block (2048 items) exclusive scan in place, emit block sums.
__global__ void scan1(int* __restrict__ wsi) {
    __shared__ int l[256];
    const int t = threadIdx.x, blk = blockIdx.x;
    const int base = WS_HIST + blk * 2048 + t * 8;
    int v[8], s = 0;
#pragma unroll
    for (int i = 0; i < 8; ++i) v[i] = wsi[base + i];
#pragma unroll
    for (int i = 0; i < 8; ++i) { int t0 = v[i]; v[i] = s; s += t0; }
    l[t] = s;
    __syncthreads();
    for (int off = 1; off < 256; off <<= 1) {
        int a = (t >= off) ? l[t - off] : 0;
        __syncthreads();
        l[t] += a;
        __syncthreads();
    }
    const int excl = t ? l[t - 1] : 0;
#pragma unroll
    for (int i = 0; i < 8; ++i) wsi[base + i] = excl + v[i];
    if (t == 255) wsi[WS_PART + blk] = l[255];
}

// Scan stage 2: exclusive scan of the 1024 block sums (single block).
__global__ void scan2(int* __restrict__ wsi) {
    __shared__ int l[256];
    const int t = threadIdx.x;
    const int base = WS_PART + t * 4;
    int v[4], s = 0;
#pragma unroll
    for (int i = 0; i < 4; ++i) v[i] = wsi[base + i];
#pragma unroll
    for (int i = 0; i < 4; ++i) { int t0 = v[i]; v[i] = s; s += t0; }
    l[t] = s;
    __syncthreads();
    for (int off = 1; off < 256; off <<= 1) {
        int a = (t >= off) ? l[t - off] : 0;
        __syncthreads();
        l[t] += a;
        __syncthreads();
    }
    const int excl = t ? l[t - 1] : 0;
#pragma unroll
    for (int i = 0; i < 4; ++i) wsi[base + i] = excl + v[i];
}

// Scan stage 3: add block offsets back; init cursors = offsets.
__global__ void scan3(int* __restrict__ wsi) {
    const int i = blockIdx.x * 2048 + threadIdx.x * 8;
    const int p = wsi[WS_PART + blockIdx.x];
#pragma unroll
    for (int k = 0; k < 8; ++k) {
        const int v = wsi[WS_HIST + i + k] + p;
        wsi[WS_HIST + i + k] = v;
        wsi[WS_CUR + i + k]  = v;
    }
}

// Scatter point ids into segments; first point of a cell appends to occupied list.
__global__ void scatter_ids(int* __restrict__ wsi) {
    const int b = blockIdx.y;
    const int n = blockIdx.x * 256 + threadIdx.x;
    if (n >= N_) return;
    const int idx = wsi[WS_CELL + b * N_ + n];
    if (idx < 0) return;
    const int pos = atomicAdd(&wsi[WS_CUR + idx], 1);
    wsi[WS_IDS + pos] = n;
    if (pos == wsi[WS_HIST + idx]) {
        const int li = atomicAdd(&wsi[WS_CNT], 1);
        wsi[WS_LIST + li] = idx;
    }
}

// Pass 2: one wave per occupied cell, lane = channel. h1 broadcast via LDS
// (wave-uniform ds_read_b128), 4-way split accumulators to break the fmaf
// chain, 2-slot software pipeline (compute h1(j+1) while consuming h1(j)).
// Plain store per (cell,channel) — no output atomics. max is commutative ->
// deterministic regardless of segment order.
__global__ __launch_bounds__(256) void cell_reduce(const float* __restrict__ pts,
                                                   const float* __restrict__ wsf,
                                                   const int* __restrict__ wsi,
                                                   float* __restrict__ out) {
    __shared__ float h1s[4][2][C_];
    const int wid = threadIdx.x >> 6;
    const int c   = threadIdx.x & 63;
    const int tw  = blockIdx.x * 4 + wid;
    const int nw  = gridDim.x * 4;

    float w1c[10];
#pragma unroll
    for (int f = 0; f < 10; ++f) w1c[f] = wsf[WS_W1T + c * 10 + f];
    const float b1c = wsf[WS_B1 + c];
    float w2c[C_];
#pragma unroll
    for (int k = 0; k < C_; ++k) w2c[k] = wsf[WS_W2T + c * C_ + k];
    const float b2c = wsf[WS_B2 + c];
    const float zm0 = wsf[WS_ZM], zm1 = wsf[WS_ZM + 1];

    const int cnt = wsi[WS_CNT];
    for (int e = tw; e < cnt; e += nw) {
        const int idx  = wsi[WS_LIST + e];
        const int b    = idx >> 20;
        const int cell = idx & (CELLS - 1);
        const float pxf = (float)(cell & (NX_ - 1));
        const float pyf = (float)(cell >> 10);
        const float zmean = b ? zm1 : zm0;
        const int start = wsi[WS_HIST + idx];
        const int end   = wsi[WS_CUR + idx];

        auto h1_of = [&](int n) -> float {
            const size_t pb = ((size_t)b * N_ + n) * 5;
            const float x = pts[pb], y = pts[pb + 1], z = pts[pb + 2];
            const float it = pts[pb + 3], rg = pts[pb + 4];
            float a = b1c;
            a = fmaf(x,  w1c[0], a);
            a = fmaf(y,  w1c[1], a);
            a = fmaf(z,  w1c[2], a);
            a = fmaf(it, w1c[3], a);
            a = fmaf(rg, w1c[4], a);
            a = fmaf(x - (pxf * VS0 + PC0 + VS0 * 0.5f), w1c[5], a);
            a = fmaf(y - (pyf * VS1 + PC1 + VS1 * 0.5f), w1c[6], a);
            a = fmaf(z - zmean,                          w1c[7], a);
            a = fmaf(x - (pxf * VS0 + PC0),              w1c[8], a);
            a = fmaf(y - (pyf * VS1 + PC1),              w1c[9], a);
            return fmaxf(a, 0.f);
        };

        h1s[wid][0][c] = h1_of(wsi[WS_IDS + start]);
        float hmax = 0.f;
        for (int j = start; j < end; ++j) {
            const int cur = (j - start) & 1;
            if (j + 1 < end) h1s[wid][cur ^ 1][c] = h1_of(wsi[WS_IDS + j + 1]);
            const f32x4* hrow = (const f32x4*)h1s[wid][cur];
            float ac0 = 0.f, ac1 = 0.f, ac2 = 0.f, ac3 = 0.f;
#pragma unroll
            for (int i = 0; i < 16; ++i) {
                const f32x4 hv = hrow[i];
                ac0 = fmaf(hv.x, w2c[4 * i + 0], ac0);
                ac1 = fmaf(hv.y, w2c[4 * i + 1], ac1);
                ac2 = fmaf(hv.z, w2c[4 * i + 2], ac2);
                ac3 = fmaf(hv.w, w2c[4 * i + 3], ac3);
            }
            hmax = fmaxf(hmax, b2c + ((ac0 + ac1) + (ac2 + ac3)));
        }
        out[(((size_t)b * C_ + c) << 20) + cell] = hmax;
    }
}

// ---------------- fallback path (round-2, atomic scatter) ----------------
__global__ void zmean_stage1(const float* __restrict__ pts, const int* __restrict__ mask,
                             float* __restrict__ ws) {
    const int b = blockIdx.y, r = blockIdx.x, t = threadIdx.x;
    constexpr int chunk = (N_ + RBLK - 1) / RBLK;
    const int start = r * chunk;
    const int end   = start + chunk < N_ ? start + chunk : N_;
    float sz = 0.f, sm = 0.f;
    for (int n = start + t; n < end; n += 256) {
        float mk = mask[b * N_ + n] ? 1.f : 0.f;
        sz += pts[((size_t)b * N_ + n) * 5 + 2] * mk;
        sm += mk;
    }
    __shared__ float lz[256], lm[256];
    lz[t] = sz; lm[t] = sm;
    __syncthreads();
    for (int s = 128; s > 0; s >>= 1) {
        if (t < s) { lz[t] += lz[t + s]; lm[t] += lm[t + s]; }
        __syncthreads();
    }
    if (t == 0) { ws[WS_PZ + b * RBLK + r] = lz[0]; ws[WS_PM + b * RBLK + r] = lm[0]; }
}

__global__ __launch_bounds__(256) void pfn_scatter(const float* __restrict__ pts,
                                                   const int* __restrict__ mask,
                                                   const float* __restrict__ ws,
                                                   float* __restrict__ out) {
    const int b = blockIdx.y;
    const int n = blockIdx.x * 256 + threadIdx.x;
    if (n >= N_) return;
    if (!mask[b * N_ + n]) return;
    const float zmean = ws[WS_ZM + b];
    const size_t pbase = ((size_t)b * N_ + n) * 5;
    const float x = pts[pbase], y = pts[pbase + 1], z = pts[pbase + 2];
    const float it = pts[pbase + 3], rg = pts[pbase + 4];
    const int cell = cell_of(x, y);
    const float pxf = (float)(cell & (NX_ - 1)), pyf = (float)(cell >> 10);
    float aug[10];
    aug[0] = x; aug[1] = y; aug[2] = z; aug[3] = it; aug[4] = rg;
    aug[5] = x - (pxf * VS0 + PC0 + VS0 * 0.5f);
    aug[6] = y - (pyf * VS1 + PC1 + VS1 * 0.5f);
    aug[7] = z - zmean;
    aug[8] = x - (pxf * VS0 + PC0);
    aug[9] = y - (pyf * VS1 + PC1);
    float h1[C_];
#pragma unroll
    for (int c = 0; c < C_; ++c) {
        float acc = ws[WS_B1 + c];
#pragma unroll
        for (int f = 0; f < 10; ++f) acc = fmaf(aug[f], ws[WS_W1T + c * 10 + f], acc);
        h1[c] = fmaxf(acc, 0.f);
    }
    unsigned int* ob = (unsigned int*)out + (size_t)b * C_ * CELLS + cell;
#pragma unroll 4
    for (int c = 0; c < C_; ++c) {
        float acc = ws[WS_B2 + c];
#pragma unroll
        for (int k = 0; k < C_; ++k) acc = fmaf(h1[k], ws[WS_W2T + c * C_ + k], acc);
        if (acc > 0.f) atomicMax(ob + (size_t)c * CELLS, __float_as_uint(acc));
    }
}

extern "C" void kernel_launch(void* const* d_in, const int* in_sizes, int n_in,
                              void* d_out, int out_size, void* d_ws, size_t ws_size,
                              hipStream_t stream) {
    const float* pts  = (const float*)d_in[0];
    const int*   mask = (const int*)d_in[1];
    const float* W1 = (const float*)d_in[2];
    const float* g1 = (const float*)d_in[3];
    const float* b1 = (const float*)d_in[4];
    const float* m1 = (const float*)d_in[5];
    const float* v1 = (const float*)d_in[6];
    const float* W2 = (const float*)d_in[7];
    const float* g2 = (const float*)d_in[8];
    const float* b2 = (const float*)d_in[9];
    const float* m2 = (const float*)d_in[10];
    const float* v2 = (const float*)d_in[11];
    float* wsf = (float*)d_ws;
    int*   wsi = (int*)d_ws;
    float* out = (float*)d_out;

    if (ws_size >= NEED_BYTES) {
        zero_bufs<<<2048, 256, 0, stream>>>((f32x4*)out, (f32x4*)(wsi + WS_HIST));
        prep_weights<<<1, 256, 0, stream>>>(W1, g1, b1, m1, v1, W2, g2, b2, m2, v2, wsf);
        zmean_hist_cell<<<dim3(RBLK, B_), 256, 0, stream>>>(pts, mask, wsf, wsi);
        zmean_stage2<<<B_, 256, 0, stream>>>(wsf);
        scan1<<<TOT / 2048, 256, 0, stream>>>(wsi);
        scan2<<<1, 256, 0, stream>>>(wsi);
        scan3<<<TOT / 2048, 256, 0, stream>>>(wsi);
        scatter_ids<<<dim3((N_ + 255) / 256, B_), 256, 0, stream>>>(wsi);
        cell_reduce<<<2048, 256, 0, stream>>>(pts, wsf, wsi, out);
    } else {
        hipMemsetAsync(d_out, 0, (size_t)out_size * sizeof(float), stream);
        prep_weights<<<1, 256, 0, stream>>>(W1, g1, b1, m1, v1, W2, g2, b2, m2, v2, wsf);
        zmean_stage1<<<dim3(RBLK, B_), 256, 0, stream>>>(pts, mask, wsf);
        zmean_stage2<<<B_, 256, 0, stream>>>(wsf);
        pfn_scatter<<<dim3((N_ + 255) / 256, B_), 256, 0, stream>>>(pts, mask, wsf, out);
    }
}

// Round 5
// 327.357 us; speedup vs baseline: 1.1898x; 1.1898x over previous
//
#include <hip/hip_runtime.h>

typedef float f32x4 __attribute__((ext_vector_type(4)));
typedef int   i32x4 __attribute__((ext_vector_type(4)));

namespace {
constexpr int   B_    = 2;
constexpr int   N_    = 250000;
constexpr int   C_    = 64;
constexpr int   NX_   = 1024;
constexpr int   NY_   = 1024;
constexpr int   CELLS = NX_ * NY_;          // 1<<20
constexpr float VS0   = 0.1f, VS1 = 0.1f;
constexpr float PC0   = -51.2f, PC1 = -51.2f;
constexpr float EPS_  = 1e-5f;
constexpr int   RBLK  = 256;

// fat-kernel role split
constexpr int   CB    = 512;    // compute blocks
constexpr int   ZB    = 1536;   // zero blocks

// ---- d_ws layout (4B units) ----
constexpr int WS_W1T  = 0;                   // [64][10]
constexpr int WS_B1   = 640;                 // [64]
constexpr int WS_W2T  = 704;                 // [64][64] (c-major rows)
constexpr int WS_B2   = 4800;                // [64]
constexpr int WS_ZM   = 4864;                // [B]
constexpr int WS_PZ   = 4872;                // [B][RBLK]
constexpr int WS_PM   = WS_PZ + B_ * RBLK;   // [B][RBLK]
constexpr int WS_CNT  = WS_PM + B_ * RBLK;   // occupied-cell counter
constexpr int WS_HIST = 8192;                // [B*CELLS] counts -> exclusive offsets
constexpr int TOT     = B_ * CELLS;          // 2,097,152
constexpr int WS_CUR  = WS_HIST + TOT;       // [B*CELLS] write cursors
constexpr int WS_PART = WS_CUR + TOT;        // [1024] scan partials
constexpr int WS_CELL = WS_PART + 2048;      // [B*N] per-point cell idx (-1 invalid)
constexpr int WS_IDS  = WS_CELL + B_ * N_;   // [<=B*N] sorted point ids
constexpr int WS_LIST = WS_IDS + B_ * N_;    // [<=B*N] occupied cell list
constexpr int WS_BMP  = WS_LIST + B_ * N_;   // [TOT/32] occupancy bitmap
constexpr int WS_END  = WS_BMP + TOT / 32;
constexpr size_t NEED_BYTES = (size_t)WS_END * 4;
}

// Zero hist + bitmap ourselves (rocclr's small-fill path runs at 26 GB/s).
__global__ __launch_bounds__(256) void zero_meta(i32x4* __restrict__ hist4,
                                                 i32x4* __restrict__ bmp4) {
    const int tid    = blockIdx.x * 256 + threadIdx.x;
    const int stride = gridDim.x * 256;
    constexpr int H4 = TOT / 4;        // 524,288
    constexpr int M4 = TOT / 32 / 4;   // 16,384
    const i32x4 z = {0, 0, 0, 0};
    for (int i = tid; i < H4; i += stride) __builtin_nontemporal_store(z, hist4 + i);
    for (int i = tid; i < M4; i += stride) __builtin_nontemporal_store(z, bmp4 + i);
}

// ---------------- common prep ----------------
__global__ void prep_weights(const float* __restrict__ W1, const float* __restrict__ g1,
                             const float* __restrict__ b1, const float* __restrict__ m1,
                             const float* __restrict__ v1, const float* __restrict__ W2,
                             const float* __restrict__ g2, const float* __restrict__ b2,
                             const float* __restrict__ m2, const float* __restrict__ v2,
                             float* __restrict__ ws) {
    int c = threadIdx.x;
    if (c == 0) ((int*)ws)[WS_CNT] = 0;
    if (c >= C_) return;
    float s1 = g1[c] / sqrtf(v1[c] + EPS_);
    for (int f = 0; f < 10; ++f) ws[WS_W1T + c * 10 + f] = W1[f * C_ + c] * s1;
    ws[WS_B1 + c] = b1[c] - m1[c] * s1;
    float s2 = g2[c] / sqrtf(v2[c] + EPS_);
    for (int k = 0; k < C_; ++k) ws[WS_W2T + c * C_ + k] = W2[k * C_ + c] * s2;
    ws[WS_B2 + c] = b2[c] - m2[c] * s2;
}

__device__ __forceinline__ int cell_of(float x, float y) {
    int px = (int)floorf((x - PC0) / VS0);
    int py = (int)floorf((y - PC1) / VS1);
    px = px < 0 ? 0 : (px > NX_ - 1 ? NX_ - 1 : px);
    py = py < 0 ? 0 : (py > NY_ - 1 ? NY_ - 1 : py);
    return py * NX_ + px;
}

// ---------------- sorted path ----------------
// Fused: z-mean partials + per-point cell id + histogram + occupancy bitmap.
__global__ void zmean_hist_cell(const float* __restrict__ pts, const int* __restrict__ mask,
                                float* __restrict__ wsf, int* __restrict__ wsi) {
    const int b = blockIdx.y, r = blockIdx.x, t = threadIdx.x;
    constexpr int chunk = (N_ + RBLK - 1) / RBLK;
    const int start = r * chunk;
    const int end   = start + chunk < N_ ? start + chunk : N_;
    float sz = 0.f, sm = 0.f;
    for (int n = start + t; n < end; n += 256) {
        const int mk = mask[b * N_ + n];
        const size_t pb = ((size_t)b * N_ + n) * 5;
        const float x = pts[pb], y = pts[pb + 1], z = pts[pb + 2];
        const int idx = b * CELLS + cell_of(x, y);
        wsi[WS_CELL + b * N_ + n] = mk ? idx : -1;
        if (mk) {
            const int old = atomicAdd(&wsi[WS_HIST + idx], 1);
            if (old == 0) atomicOr(&wsi[WS_BMP + (idx >> 5)], 1 << (idx & 31));
            sz += z; sm += 1.f;
        }
    }
    __shared__ float lz[256], lm[256];
    lz[t] = sz; lm[t] = sm;
    __syncthreads();
    for (int s = 128; s > 0; s >>= 1) {
        if (t < s) { lz[t] += lz[t + s]; lm[t] += lm[t + s]; }
        __syncthreads();
    }
    if (t == 0) { wsf[WS_PZ + b * RBLK + r] = lz[0]; wsf[WS_PM + b * RBLK + r] = lm[0]; }
}

__global__ void zmean_stage2(float* __restrict__ ws) {
    const int b = blockIdx.x, t = threadIdx.x;
    __shared__ float lz[256], lm[256];
    lz[t] = ws[WS_PZ + b * RBLK + t];
    lm[t] = ws[WS_PM + b * RBLK + t];
    __syncthreads();
    for (int s = 128; s > 0; s >>= 1) {
        if (t < s) { lz[t] += lz[t + s]; lm[t] += lm[t + s]; }
        __syncthreads();
    }
    if (t == 0) ws[WS_ZM + b] = lz[0] / fmaxf(lm[0], 1.f);
}

// Scan stage 1: per-block (2048 items) exclusive scan in place, emit block sums.
__global__ void scan1(int* __restrict__ wsi) {
    __shared__ int l[256];
    const int t = threadIdx.x, blk = blockIdx.x;
    const int base = WS_HIST + blk * 2048 + t * 8;
    int v[8], s = 0;
#pragma unroll
    for (int i = 0; i < 8; ++i) v[i] = wsi[base + i];
#pragma unroll
    for (int i = 0; i < 8; ++i) { int t0 = v[i]; v[i] = s; s += t0; }
    l[t] = s;
    __syncthreads();
    for (int off = 1; off < 256; off <<= 1) {
        int a = (t >= off) ? l[t - off] : 0;
        __syncthreads();
        l[t] += a;
        __syncthreads();
    }
    const int excl = t ? l[t - 1] : 0;
#pragma unroll
    for (int i = 0; i < 8; ++i) wsi[base + i] = excl + v[i];
    if (t == 255) wsi[WS_PART + blk] = l[255];
}

// Scan stage 2: exclusive scan of the 1024 block sums (single block).
__global__ void scan2(int* __restrict__ wsi) {
    __shared__ int l[256];
    const int t = threadIdx.x;
    const int base = WS_PART + t * 4;
    int v[4], s = 0;
#pragma unroll
    for (int i = 0; i < 4; ++i) v[i] = wsi[base + i];
#pragma unroll
    for (int i = 0; i < 4; ++i) { int t0 = v[i]; v[i] = s; s += t0; }
    l[t] = s;
    __syncthreads();
    for (int off = 1; off < 256; off <<= 1) {
        int a = (t >= off) ? l[t - off] : 0;
        __syncthreads();
        l[t] += a;
        __syncthreads();
    }
    const int excl = t ? l[t - 1] : 0;
#pragma unroll
    for (int i = 0; i < 4; ++i) wsi[base + i] = excl + v[i];
}

// Scan stage 3: add block offsets back; init cursors = offsets.
__global__ void scan3(int* __restrict__ wsi) {
    const int i = blockIdx.x * 2048 + threadIdx.x * 8;
    const int p = wsi[WS_PART + blockIdx.x];
#pragma unroll
    for (int k = 0; k < 8; ++k) {
        const int v = wsi[WS_HIST + i + k] + p;
        wsi[WS_HIST + i + k] = v;
        wsi[WS_CUR + i + k]  = v;
    }
}

// Scatter point ids into segments; first point of a cell appends to occupied list.
__global__ void scatter_ids(int* __restrict__ wsi) {
    const int b = blockIdx.y;
    const int n = blockIdx.x * 256 + threadIdx.x;
    if (n >= N_) return;
    const int idx = wsi[WS_CELL + b * N_ + n];
    if (idx < 0) return;
    const int pos = atomicAdd(&wsi[WS_CUR + idx], 1);
    wsi[WS_IDS + pos] = n;
    if (pos == wsi[WS_HIST + idx]) {
        const int li = atomicAdd(&wsi[WS_CNT], 1);
        wsi[WS_LIST + li] = idx;
    }
}

// Fat kernel: blocks [0,CB) compute occupied cells (wave=cell, lane=channel);
// blocks [CB,CB+ZB) zero all non-occupied cells with NT stores, skipping
// occupied ones via the bitmap. Store sets are DISJOINT -> no ordering needed,
// output bitwise deterministic (max commutes; one writer per word).
__global__ __launch_bounds__(256) void fused_zero_compute(const float* __restrict__ pts,
                                                          const float* __restrict__ wsf,
                                                          const int* __restrict__ wsi,
                                                          float* __restrict__ out) {
    if (blockIdx.x < CB) {
        // ---- compute role ----
        __shared__ float h1s[4][C_];
        const int wid = threadIdx.x >> 6;
        const int c   = threadIdx.x & 63;
        const int tw  = blockIdx.x * 4 + wid;
        const int nw  = CB * 4;

        float w1c[10];
#pragma unroll
        for (int f = 0; f < 10; ++f) w1c[f] = wsf[WS_W1T + c * 10 + f];
        const float b1c = wsf[WS_B1 + c];
        float w2c[C_];
#pragma unroll
        for (int k = 0; k < C_; ++k) w2c[k] = wsf[WS_W2T + c * C_ + k];
        const float b2c = wsf[WS_B2 + c];
        const float zm0 = wsf[WS_ZM], zm1 = wsf[WS_ZM + 1];

        const int cnt = wsi[WS_CNT];
        for (int e = tw; e < cnt; e += nw) {
            const int idx  = wsi[WS_LIST + e];
            const int b    = idx >> 20;
            const int cell = idx & (CELLS - 1);
            const float pxf = (float)(cell & (NX_ - 1));
            const float pyf = (float)(cell >> 10);
            const float zmean = b ? zm1 : zm0;
            const int start = wsi[WS_HIST + idx];
            const int end   = wsi[WS_CUR + idx];
            float hmax = 0.f;
            for (int j = start; j < end; ++j) {
                const int n = wsi[WS_IDS + j];
                const size_t pb = ((size_t)b * N_ + n) * 5;
                const float x = pts[pb], y = pts[pb + 1], z = pts[pb + 2];
                const float it = pts[pb + 3], rg = pts[pb + 4];
                float a = b1c;
                a = fmaf(x,  w1c[0], a);
                a = fmaf(y,  w1c[1], a);
                a = fmaf(z,  w1c[2], a);
                a = fmaf(it, w1c[3], a);
                a = fmaf(rg, w1c[4], a);
                a = fmaf(x - (pxf * VS0 + PC0 + VS0 * 0.5f), w1c[5], a);
                a = fmaf(y - (pyf * VS1 + PC1 + VS1 * 0.5f), w1c[6], a);
                a = fmaf(z - zmean,                          w1c[7], a);
                a = fmaf(x - (pxf * VS0 + PC0),              w1c[8], a);
                a = fmaf(y - (pyf * VS1 + PC1),              w1c[9], a);
                h1s[wid][c] = fmaxf(a, 0.f);
                const f32x4* hrow = (const f32x4*)h1s[wid];
                float ac0 = 0.f, ac1 = 0.f, ac2 = 0.f, ac3 = 0.f;
#pragma unroll
                for (int i = 0; i < 16; ++i) {
                    const f32x4 hv = hrow[i];
                    ac0 = fmaf(hv.x, w2c[4 * i + 0], ac0);
                    ac1 = fmaf(hv.y, w2c[4 * i + 1], ac1);
                    ac2 = fmaf(hv.z, w2c[4 * i + 2], ac2);
                    ac3 = fmaf(hv.w, w2c[4 * i + 3], ac3);
                }
                hmax = fmaxf(hmax, b2c + ((ac0 + ac1) + (ac2 + ac3)));
            }
            out[(((size_t)b * C_ + c) << 20) + cell] = hmax;
        }
    } else {
        // ---- zero role ----
        constexpr int N4 = (B_ * C_ * CELLS) / 4;   // 33,554,432 f32x4
        const int tid    = (blockIdx.x - CB) * 256 + threadIdx.x;
        const int stride = ZB * 256;
        f32x4* out4 = (f32x4*)out;
        const f32x4 z = {0.f, 0.f, 0.f, 0.f};
        for (int i = tid; i < N4; i += stride) {
            const int L     = i << 2;               // linear float idx (fits: <2^27... use int64 for addr)
            const int cell0 = L & (CELLS - 1);
            const int plane = (int)(((unsigned)i) >> 18);  // L>>20 = i>>18
            const int b     = plane >> 6;
            const unsigned w = (unsigned)wsi[WS_BMP + ((b << 20 | cell0) >> 5)];
            const unsigned nib = (w >> (cell0 & 31)) & 0xFu;
            if (nib == 0u) {
                __builtin_nontemporal_store(z, out4 + i);
            } else {
#pragma unroll
                for (int jj = 0; jj < 4; ++jj)
                    if (!((nib >> jj) & 1u)) out[(size_t)i * 4 + jj] = 0.f;
            }
        }
    }
}

// ---------------- fallback path (round-2, atomic scatter) ----------------
__global__ void zmean_stage1(const float* __restrict__ pts, const int* __restrict__ mask,
                             float* __restrict__ ws) {
    const int b = blockIdx.y, r = blockIdx.x, t = threadIdx.x;
    constexpr int chunk = (N_ + RBLK - 1) / RBLK;
    const int start = r * chunk;
    const int end   = start + chunk < N_ ? start + chunk : N_;
    float sz = 0.f, sm = 0.f;
    for (int n = start + t; n < end; n += 256) {
        float mk = mask[b * N_ + n] ? 1.f : 0.f;
        sz += pts[((size_t)b * N_ + n) * 5 + 2] * mk;
        sm += mk;
    }
    __shared__ float lz[256], lm[256];
    lz[t] = sz; lm[t] = sm;
    __syncthreads();
    for (int s = 128; s > 0; s >>= 1) {
        if (t < s) { lz[t] += lz[t + s]; lm[t] += lm[t + s]; }
        __syncthreads();
    }
    if (t == 0) { ws[WS_PZ + b * RBLK + r] = lz[0]; ws[WS_PM + b * RBLK + r] = lm[0]; }
}

__global__ __launch_bounds__(256) void pfn_scatter(const float* __restrict__ pts,
                                                   const int* __restrict__ mask,
                                                   const float* __restrict__ ws,
                                                   float* __restrict__ out) {
    const int b = blockIdx.y;
    const int n = blockIdx.x * 256 + threadIdx.x;
    if (n >= N_) return;
    if (!mask[b * N_ + n]) return;
    const float zmean = ws[WS_ZM + b];
    const size_t pbase = ((size_t)b * N_ + n) * 5;
    const float x = pts[pbase], y = pts[pbase + 1], z = pts[pbase + 2];
    const float it = pts[pbase + 3], rg = pts[pbase + 4];
    const int cell = cell_of(x, y);
    const float pxf = (float)(cell & (NX_ - 1)), pyf = (float)(cell >> 10);
    float aug[10];
    aug[0] = x; aug[1] = y; aug[2] = z; aug[3] = it; aug[4] = rg;
    aug[5] = x - (pxf * VS0 + PC0 + VS0 * 0.5f);
    aug[6] = y - (pyf * VS1 + PC1 + VS1 * 0.5f);
    aug[7] = z - zmean;
    aug[8] = x - (pxf * VS0 + PC0);
    aug[9] = y - (pyf * VS1 + PC1);
    float h1[C_];
#pragma unroll
    for (int c = 0; c < C_; ++c) {
        float acc = ws[WS_B1 + c];
#pragma unroll
        for (int f = 0; f < 10; ++f) acc = fmaf(aug[f], ws[WS_W1T + c * 10 + f], acc);
        h1[c] = fmaxf(acc, 0.f);
    }
    unsigned int* ob = (unsigned int*)out + (size_t)b * C_ * CELLS + cell;
#pragma unroll 4
    for (int c = 0; c < C_; ++c) {
        float acc = ws[WS_B2 + c];
#pragma unroll
        for (int k = 0; k < C_; ++k) acc = fmaf(h1[k], ws[WS_W2T + c * C_ + k], acc);
        if (acc > 0.f) atomicMax(ob + (size_t)c * CELLS, __float_as_uint(acc));
    }
}

extern "C" void kernel_launch(void* const* d_in, const int* in_sizes, int n_in,
                              void* d_out, int out_size, void* d_ws, size_t ws_size,
                              hipStream_t stream) {
    const float* pts  = (const float*)d_in[0];
    const int*   mask = (const int*)d_in[1];
    const float* W1 = (const float*)d_in[2];
    const float* g1 = (const float*)d_in[3];
    const float* b1 = (const float*)d_in[4];
    const float* m1 = (const float*)d_in[5];
    const float* v1 = (const float*)d_in[6];
    const float* W2 = (const float*)d_in[7];
    const float* g2 = (const float*)d_in[8];
    const float* b2 = (const float*)d_in[9];
    const float* m2 = (const float*)d_in[10];
    const float* v2 = (const float*)d_in[11];
    float* wsf = (float*)d_ws;
    int*   wsi = (int*)d_ws;
    float* out = (float*)d_out;

    if (ws_size >= NEED_BYTES) {
        zero_meta<<<512, 256, 0, stream>>>((i32x4*)(wsi + WS_HIST), (i32x4*)(wsi + WS_BMP));
        prep_weights<<<1, 256, 0, stream>>>(W1, g1, b1, m1, v1, W2, g2, b2, m2, v2, wsf);
        zmean_hist_cell<<<dim3(RBLK, B_), 256, 0, stream>>>(pts, mask, wsf, wsi);
        zmean_stage2<<<B_, 256, 0, stream>>>(wsf);
        scan1<<<TOT / 2048, 256, 0, stream>>>(wsi);
        scan2<<<1, 256, 0, stream>>>(wsi);
        scan3<<<TOT / 2048, 256, 0, stream>>>(wsi);
        scatter_ids<<<dim3((N_ + 255) / 256, B_), 256, 0, stream>>>(wsi);
        fused_zero_compute<<<CB + ZB, 256, 0, stream>>>(pts, wsf, wsi, out);
    } else {
        hipMemsetAsync(d_out, 0, (size_t)out_size * sizeof(float), stream);
        prep_weights<<<1, 256, 0, stream>>>(W1, g1, b1, m1, v1, W2, g2, b2, m2, v2, wsf);
        zmean_stage1<<<dim3(RBLK, B_), 256, 0, stream>>>(pts, mask, wsf);
        zmean_stage2<<<B_, 256, 0, stream>>>(wsf);
        pfn_scatter<<<dim3((N_ + 255) / 256, B_), 256, 0, stream>>>(pts, mask, wsf, out);
    }
}